// Round 4
// baseline (357.147 us; speedup 1.0000x reference)
//
#include <hip/hip_runtime.h>
#include <hip/hip_bf16.h>

// Self-attention with softmax over the QUERY axis (dim=1):
//   Q=XWq^T K=XWk^T V=XWv^T ; s = QK^T/16 ; attn[:,q,k] = exp(s)/sum_q exp(s)
//   out = attn @ V
// B=4, S=4096, D=Q_DIM=256.
//
// Path A (ws >= ~168MB): materialize P=exp(s/16) bf16 in ws; PV = plain GEMM
//   with register double-buffered pipeline (k-chunk 128, launch_bounds(512,2)
//   so 256-VGPR budget; sched_barrier pins loads above MFMAs).
// Path B: flash-style fallback.

#define BATCH 4
#define SEQ 4096
#define DIM 256
#define ROWS (BATCH * SEQ)   // 16384

typedef __bf16 bf16x8 __attribute__((ext_vector_type(8)));
typedef float f32x4 __attribute__((ext_vector_type(4)));

__device__ __forceinline__ unsigned short f2b(float f) {
    union { float f; unsigned u; } v; v.f = f;
    unsigned u = v.u;
    u += 0x7FFFu + ((u >> 16) & 1u);   // RNE
    return (unsigned short)(u >> 16);
}

__device__ __forceinline__ float b2f(unsigned short h) {
    union { unsigned u; float f; } v; v.u = ((unsigned)h) << 16;
    return v.f;
}

// ---------------- vectorized cast f32 -> bf16 (n multiple of 8) ----------------
__global__ void cast_v8(const float* __restrict__ in,
                        unsigned short* __restrict__ out, int n8) {
    int i = blockIdx.x * blockDim.x + threadIdx.x;
    if (i >= n8) return;
    const float4 f0 = *(const float4*)(in + (size_t)i * 8);
    const float4 f1 = *(const float4*)(in + (size_t)i * 8 + 4);
    union { unsigned short u[8]; bf16x8 v; } o;
    o.u[0] = f2b(f0.x); o.u[1] = f2b(f0.y); o.u[2] = f2b(f0.z); o.u[3] = f2b(f0.w);
    o.u[4] = f2b(f1.x); o.u[5] = f2b(f1.y); o.u[6] = f2b(f1.z); o.u[7] = f2b(f1.w);
    *(bf16x8*)(out + (size_t)i * 8) = o.v;
}

// weights: 3 arrays of 65536 cast in one launch
__global__ void cast_w3(const float* __restrict__ w0, const float* __restrict__ w1,
                        const float* __restrict__ w2, unsigned short* __restrict__ o0,
                        unsigned short* __restrict__ o1, unsigned short* __restrict__ o2) {
    int t = blockIdx.x * blockDim.x + threadIdx.x;   // 3 * 8192
    int arr = t >> 13;
    int i = (t & 8191);
    const float* in = arr == 0 ? w0 : arr == 1 ? w1 : w2;
    unsigned short* out = arr == 0 ? o0 : arr == 1 ? o1 : o2;
    const float4 f0 = *(const float4*)(in + (size_t)i * 8);
    const float4 f1 = *(const float4*)(in + (size_t)i * 8 + 4);
    union { unsigned short u[8]; bf16x8 v; } o;
    o.u[0] = f2b(f0.x); o.u[1] = f2b(f0.y); o.u[2] = f2b(f0.z); o.u[3] = f2b(f0.w);
    o.u[4] = f2b(f1.x); o.u[5] = f2b(f1.y); o.u[6] = f2b(f1.z); o.u[7] = f2b(f1.w);
    *(bf16x8*)(out + (size_t)i * 8) = o.v;
}

// ------- QKV GEMM: z=0 Q, z=1 K, z=2 V(transposed store). out = X(Mx256)*W^T -------
__global__ __launch_bounds__(256) void gemm_qkv(const unsigned short* __restrict__ X,
                                                const unsigned short* __restrict__ Wq,
                                                const unsigned short* __restrict__ Wk,
                                                const unsigned short* __restrict__ Wv,
                                                unsigned short* __restrict__ Qo,
                                                unsigned short* __restrict__ Ko,
                                                unsigned short* __restrict__ Vo) {
    const int z = blockIdx.z;
    const unsigned short* Bw = z == 0 ? Wq : z == 1 ? Wk : Wv;
    unsigned short* out = z == 0 ? Qo : z == 1 ? Ko : Vo;
    const int trans = (z == 2);

    const int l = threadIdx.x & 63;
    const int w = threadIdx.x >> 6;
    const int wr = w >> 1, wc = w & 1;
    const int lr = l & 15, lk = l >> 4;
    const int rbase = blockIdx.x * 128 + wr * 64;
    const int cbase = blockIdx.y * 128 + wc * 64;

    f32x4 acc[4][4] = {};
#pragma unroll
    for (int d0 = 0; d0 < 256; d0 += 32) {
        bf16x8 a[4], b[4];
#pragma unroll
        for (int i = 0; i < 4; ++i)
            a[i] = *(const bf16x8*)(X + (size_t)(rbase + i * 16 + lr) * 256 + d0 + lk * 8);
#pragma unroll
        for (int j = 0; j < 4; ++j)
            b[j] = *(const bf16x8*)(Bw + (size_t)(cbase + j * 16 + lr) * 256 + d0 + lk * 8);
#pragma unroll
        for (int i = 0; i < 4; ++i)
#pragma unroll
            for (int j = 0; j < 4; ++j)
                acc[i][j] = __builtin_amdgcn_mfma_f32_16x16x32_bf16(a[i], b[j], acc[i][j], 0, 0, 0);
    }
#pragma unroll
    for (int i = 0; i < 4; ++i)
#pragma unroll
        for (int j = 0; j < 4; ++j)
#pragma unroll
            for (int r = 0; r < 4; ++r) {
                int row = rbase + i * 16 + lk * 4 + r;
                int col = cbase + j * 16 + lr;
                unsigned short v = f2b(acc[i][j][r]);
                if (!trans) out[(size_t)row * DIM + col] = v;
                else        out[(size_t)col * ROWS + row] = v;
            }
}

// ================= PATH A =================
// s-tile 128q x 128k; P=exp(s/16) -> LDS -> coalesced bf16x8 store to ws;
// column partial sums -> atomicAdd lsum. grid (32 k, 32 q, 4 b), block 256.
__global__ __launch_bounds__(256) void sp_kernel(const unsigned short* __restrict__ Qb,
                                                 const unsigned short* __restrict__ Kb,
                                                 unsigned short* __restrict__ P,
                                                 float* __restrict__ lsum) {
    __shared__ unsigned short Pt[128][136];   // 272B row stride: 16B-aligned, banks shift 4/row
    const int l = threadIdx.x & 63;
    const int w = threadIdx.x >> 6;
    const int wr = w >> 1, wc = w & 1;
    const int lr = l & 15, lk = l >> 4;
    const int b = blockIdx.z;
    const int kb0 = blockIdx.x * 128;
    const int qb0 = blockIdx.y * 128;
    const int kbase = kb0 + wc * 64;
    const int qbase = qb0 + wr * 64;
    const unsigned short* Q = Qb + (size_t)b * SEQ * 256;
    const unsigned short* K = Kb + (size_t)b * SEQ * 256;
    unsigned short* Pb = P + (size_t)b * SEQ * SEQ;

    f32x4 acc[4][4] = {};
#pragma unroll
    for (int d0 = 0; d0 < 256; d0 += 32) {
        bf16x8 a[4], bb[4];
#pragma unroll
        for (int i = 0; i < 4; ++i)
            a[i] = *(const bf16x8*)(Q + (size_t)(qbase + i * 16 + lr) * 256 + d0 + lk * 8);
#pragma unroll
        for (int j = 0; j < 4; ++j)
            bb[j] = *(const bf16x8*)(K + (size_t)(kbase + j * 16 + lr) * 256 + d0 + lk * 8);
#pragma unroll
        for (int i = 0; i < 4; ++i)
#pragma unroll
            for (int j = 0; j < 4; ++j)
                acc[i][j] = __builtin_amdgcn_mfma_f32_16x16x32_bf16(a[i], bb[j], acc[i][j], 0, 0, 0);
    }
#pragma unroll
    for (int j = 0; j < 4; ++j) {
        float cs = 0.f;
#pragma unroll
        for (int i = 0; i < 4; ++i)
#pragma unroll
            for (int r = 0; r < 4; ++r) {
                float v = __expf(acc[i][j][r] * 0.0625f);
                cs += v;
                Pt[wr * 64 + i * 16 + lk * 4 + r][wc * 64 + j * 16 + lr] = f2b(v);
            }
        cs += __shfl_xor(cs, 16, 64);
        cs += __shfl_xor(cs, 32, 64);
        if (lk == 0)
            atomicAdd(&lsum[(size_t)b * SEQ + kbase + j * 16 + lr], cs);
    }
    __syncthreads();
    // cooperative coalesced store: 128 rows x 16 chunks(16B), 8 iters x 256 thr
#pragma unroll
    for (int it = 0; it < 8; ++it) {
        int n = it * 256 + threadIdx.x;
        int row = n >> 4;
        int ch = n & 15;
        *(bf16x8*)(Pb + (size_t)(qb0 + row) * SEQ + kb0 + ch * 8) =
            *(const bf16x8*)(&Pt[row][ch * 8]);
    }
}

// scale Vt rows by 1/l (vectorized x8): Vt[v][b*S+k] *= 1/l[b*S+k]
__global__ void scale_vt(unsigned short* __restrict__ Vt,
                         const float* __restrict__ lsum, int n8) {
    int i = blockIdx.x * blockDim.x + threadIdx.x;
    if (i >= n8) return;
    int col8 = (i & (ROWS / 8 - 1)) * 8;   // column base within [0,ROWS)
    union { unsigned short u[8]; bf16x8 v; } d;
    d.v = *(const bf16x8*)(Vt + (size_t)i * 8);
#pragma unroll
    for (int j = 0; j < 8; ++j)
        d.u[j] = f2b(b2f(d.u[j]) / lsum[col8 + j]);
    *(bf16x8*)(Vt + (size_t)i * 8) = d.v;
}

// PV GEMM: out[b,q,v] = sum_k P[b,q,k] * Vts[v][b*S+k]
// tile 128q x 128v, 512 thr = 8 waves (4x2). Register double-buffer with
// k-chunk 128; launch_bounds(512,2) -> 1 block/CU, 256-VGPR budget.
__global__ __launch_bounds__(512, 2) void pv_gemm(const unsigned short* __restrict__ P,
                                                  const unsigned short* __restrict__ Vt,
                                                  float* __restrict__ out) {
    const int l = threadIdx.x & 63;
    const int w = threadIdx.x >> 6;
    const int wr = w >> 1, wc = w & 1;   // 4 q-waves x 2 v-waves
    const int lr = l & 15, lk = l >> 4;
    const int b = blockIdx.z;
    const int qbase = blockIdx.x * 128 + wr * 32;
    const int vbase = blockIdx.y * 128 + wc * 64;
    const unsigned short* Pb = P + (size_t)b * SEQ * SEQ;

    const unsigned short* pA[2];
    const unsigned short* pV[4];
#pragma unroll
    for (int i = 0; i < 2; ++i)
        pA[i] = Pb + (size_t)(qbase + i * 16 + lr) * SEQ + lk * 8;
#pragma unroll
    for (int j = 0; j < 4; ++j)
        pV[j] = Vt + (size_t)(vbase + j * 16 + lr) * ROWS + (size_t)b * SEQ + lk * 8;

    // two register buffers, k-chunk 128 each (4 sub-steps of 32)
    bf16x8 aA[2][4], bA[4][4], aB[2][4], bB[4][4];

#define LOADBUF(av, bv, k0) do {                                          \
        _Pragma("unroll")                                                 \
        for (int c = 0; c < 4; ++c) {                                     \
            _Pragma("unroll")                                             \
            for (int i = 0; i < 2; ++i)                                   \
                av[i][c] = *(const bf16x8*)(pA[i] + (k0) + c * 32);       \
            _Pragma("unroll")                                             \
            for (int j = 0; j < 4; ++j)                                   \
                bv[j][c] = *(const bf16x8*)(pV[j] + (k0) + c * 32);       \
        }                                                                 \
    } while (0)

#define MMBUF(av, bv) do {                                                \
        _Pragma("unroll")                                                 \
        for (int c = 0; c < 4; ++c)                                       \
            _Pragma("unroll")                                             \
            for (int i = 0; i < 2; ++i)                                   \
                _Pragma("unroll")                                         \
                for (int j = 0; j < 4; ++j)                               \
                    acc[i][j] = __builtin_amdgcn_mfma_f32_16x16x32_bf16(  \
                        av[i][c], bv[j][c], acc[i][j], 0, 0, 0);          \
    } while (0)

    f32x4 acc[2][4] = {};
    LOADBUF(aA, bA, 0);
    for (int kt = 0; kt < SEQ; kt += 256) {
        LOADBUF(aB, bB, (kt + 128) & (SEQ - 1));
        __builtin_amdgcn_sched_barrier(0);   // keep B-loads above A-MFMAs
        MMBUF(aA, bA);
        LOADBUF(aA, bA, (kt + 256) & (SEQ - 1));   // last iter wraps to 0, unused
        __builtin_amdgcn_sched_barrier(0);   // keep A-loads above B-MFMAs
        MMBUF(aB, bB);
    }
#undef LOADBUF
#undef MMBUF

    float* O = out + (size_t)b * SEQ * 256;
#pragma unroll
    for (int i = 0; i < 2; ++i)
#pragma unroll
        for (int j = 0; j < 4; ++j)
#pragma unroll
            for (int r = 0; r < 4; ++r) {
                int row = qbase + i * 16 + lk * 4 + r;
                int col = vbase + j * 16 + lr;
                O[(size_t)row * 256 + col] = acc[i][j][r];
            }
}

// ================= PATH B (fallback) =================
__global__ __launch_bounds__(256) void colsumexp(const unsigned short* __restrict__ Qb,
                                                 const unsigned short* __restrict__ Kb,
                                                 float* __restrict__ lsum) {
    const int l = threadIdx.x & 63;
    const int w = threadIdx.x >> 6;
    const int wr = w >> 1, wc = w & 1;
    const int lr = l & 15, lk = l >> 4;
    const int b = blockIdx.z;
    const int cbase = blockIdx.x * 128 + wc * 64;
    const unsigned short* Q = Qb + (size_t)b * SEQ * 256;
    const unsigned short* K = Kb + (size_t)b * SEQ * 256;

    float csum[4] = {0.f, 0.f, 0.f, 0.f};
    for (int qi = 0; qi < 16; ++qi) {
        const int rbase = blockIdx.y * 2048 + qi * 128 + wr * 64;
        f32x4 acc[4][4] = {};
#pragma unroll
        for (int d0 = 0; d0 < 256; d0 += 32) {
            bf16x8 a[4], bb[4];
#pragma unroll
            for (int i = 0; i < 4; ++i)
                a[i] = *(const bf16x8*)(Q + (size_t)(rbase + i * 16 + lr) * 256 + d0 + lk * 8);
#pragma unroll
            for (int j = 0; j < 4; ++j)
                bb[j] = *(const bf16x8*)(K + (size_t)(cbase + j * 16 + lr) * 256 + d0 + lk * 8);
#pragma unroll
            for (int i = 0; i < 4; ++i)
#pragma unroll
                for (int j = 0; j < 4; ++j)
                    acc[i][j] = __builtin_amdgcn_mfma_f32_16x16x32_bf16(a[i], bb[j], acc[i][j], 0, 0, 0);
        }
#pragma unroll
        for (int j = 0; j < 4; ++j) {
            float s = 0.f;
#pragma unroll
            for (int i = 0; i < 4; ++i)
#pragma unroll
                for (int r = 0; r < 4; ++r)
                    s += __expf(acc[i][j][r] * 0.0625f);
            csum[j] += s;
        }
    }
#pragma unroll
    for (int j = 0; j < 4; ++j) {
        float s = csum[j];
        s += __shfl_xor(s, 16, 64);
        s += __shfl_xor(s, 32, 64);
        if (lk == 0)
            atomicAdd(&lsum[(size_t)b * SEQ + cbase + j * 16 + lr], s);
    }
}

__global__ __launch_bounds__(256) void pv_kernel(const unsigned short* __restrict__ Qb,
                                                 const unsigned short* __restrict__ Kb,
                                                 const unsigned short* __restrict__ Vt,
                                                 float* __restrict__ out) {
    __shared__ unsigned short Pl[128][72];
    const int l = threadIdx.x & 63;
    const int w = threadIdx.x >> 6;
    const int wr = w >> 1, wc = w & 1;
    const int lr = l & 15, lk = l >> 4;
    const int b = blockIdx.z;
    const int qbase = blockIdx.x * 128;
    const int vbase = blockIdx.y * 128;
    const unsigned short* Q = Qb + (size_t)b * SEQ * 256;
    const unsigned short* K = Kb + (size_t)b * SEQ * 256;
    const unsigned short* V = Vt + (size_t)b * SEQ;

    f32x4 oacc[4][4] = {};
    for (int k0 = 0; k0 < SEQ; k0 += 64) {
        f32x4 sacc[4][2] = {};
#pragma unroll
        for (int d0 = 0; d0 < 256; d0 += 32) {
            bf16x8 a[4], bb[2];
#pragma unroll
            for (int i = 0; i < 4; ++i)
                a[i] = *(const bf16x8*)(Q + (size_t)(qbase + wr * 64 + i * 16 + lr) * 256 + d0 + lk * 8);
#pragma unroll
            for (int j = 0; j < 2; ++j)
                bb[j] = *(const bf16x8*)(K + (size_t)(k0 + wc * 32 + j * 16 + lr) * 256 + d0 + lk * 8);
#pragma unroll
            for (int i = 0; i < 4; ++i)
#pragma unroll
                for (int j = 0; j < 2; ++j)
                    sacc[i][j] = __builtin_amdgcn_mfma_f32_16x16x32_bf16(a[i], bb[j], sacc[i][j], 0, 0, 0);
        }
#pragma unroll
        for (int i = 0; i < 4; ++i)
#pragma unroll
            for (int j = 0; j < 2; ++j)
#pragma unroll
                for (int r = 0; r < 4; ++r)
                    Pl[wr * 64 + i * 16 + lk * 4 + r][wc * 32 + j * 16 + lr] =
                        f2b(__expf(sacc[i][j][r] * 0.0625f));
        __syncthreads();
#pragma unroll
        for (int ks = 0; ks < 2; ++ks) {
            bf16x8 a[4], bb[4];
#pragma unroll
            for (int i = 0; i < 4; ++i)
                a[i] = *(const bf16x8*)(&Pl[wr * 64 + i * 16 + lr][ks * 32 + lk * 8]);
#pragma unroll
            for (int j = 0; j < 4; ++j)
                bb[j] = *(const bf16x8*)(V + (size_t)(vbase + wc * 64 + j * 16 + lr) * ROWS + k0 + ks * 32 + lk * 8);
#pragma unroll
            for (int i = 0; i < 4; ++i)
#pragma unroll
                for (int j = 0; j < 4; ++j)
                    oacc[i][j] = __builtin_amdgcn_mfma_f32_16x16x32_bf16(a[i], bb[j], oacc[i][j], 0, 0, 0);
        }
        __syncthreads();
    }
    float* O = out + (size_t)b * SEQ * 256;
#pragma unroll
    for (int i = 0; i < 4; ++i)
#pragma unroll
        for (int j = 0; j < 4; ++j)
#pragma unroll
            for (int r = 0; r < 4; ++r) {
                int row = qbase + wr * 64 + i * 16 + lk * 4 + r;
                int col = vbase + wc * 64 + j * 16 + lr;
                O[(size_t)row * 256 + col] = oacc[i][j][r];
            }
}

extern "C" void kernel_launch(void* const* d_in, const int* in_sizes, int n_in,
                              void* d_out, int out_size, void* d_ws, size_t ws_size,
                              hipStream_t stream) {
    const float* x  = (const float*)d_in[0];
    const float* wq = (const float*)d_in[1];
    const float* wk = (const float*)d_in[2];
    const float* wv = (const float*)d_in[3];
    float* out = (float*)d_out;

    char* ws = (char*)d_ws;
    unsigned short* Xb  = (unsigned short*)(ws + 0);
    unsigned short* Qb  = (unsigned short*)(ws + 8388608);
    unsigned short* Kb  = (unsigned short*)(ws + 16777216);
    unsigned short* Vt  = (unsigned short*)(ws + 25165824);
    unsigned short* Wqb = (unsigned short*)(ws + 33554432);
    unsigned short* Wkb = (unsigned short*)(ws + 33685504);
    unsigned short* Wvb = (unsigned short*)(ws + 33816576);
    float*          lsum = (float*)(ws + 33947648);
    unsigned short* Pbuf = (unsigned short*)(ws + 34013184);
    const size_t need_A = 34013184 + (size_t)BATCH * SEQ * SEQ * 2;   // ~168 MB

    const int n_x = ROWS * DIM;      // 4194304

    cast_v8<<<(n_x / 8 + 255) / 256, 256, 0, stream>>>(x, Xb, n_x / 8);
    cast_w3<<<(3 * 8192 + 255) / 256, 256, 0, stream>>>(wq, wk, wv, Wqb, Wkb, Wvb);

    dim3 gg(ROWS / 128, DIM / 128, 3);   // (128, 2, 3)
    gemm_qkv<<<gg, 256, 0, stream>>>(Xb, Wqb, Wkb, Wvb, Qb, Kb, Vt);

    hipMemsetAsync(lsum, 0, (size_t)BATCH * SEQ * sizeof(float), stream);

    if (ws_size >= need_A) {
        dim3 gs(SEQ / 128, SEQ / 128, BATCH);   // (32, 32, 4)
        sp_kernel<<<gs, 256, 0, stream>>>(Qb, Kb, Pbuf, lsum);
        scale_vt<<<(n_x / 8 + 255) / 256, 256, 0, stream>>>(Vt, lsum, n_x / 8);
        dim3 gp(SEQ / 128, DIM / 128, BATCH);   // (32, 2, 4)
        pv_gemm<<<gp, 512, 0, stream>>>(Pbuf, Vt, out);
    } else {
        dim3 gs(SEQ / 128, 2, BATCH);
        colsumexp<<<gs, 256, 0, stream>>>(Qb, Kb, lsum);
        scale_vt<<<(n_x / 8 + 255) / 256, 256, 0, stream>>>(Vt, lsum, n_x / 8);
        dim3 gp(SEQ / 128, DIM / 128, BATCH);
        pv_kernel<<<gp, 256, 0, stream>>>(Qb, Kb, Vt, out);
    }
}

// Round 5
// 219.991 us; speedup vs baseline: 1.6235x; 1.6235x over previous
//
#include <hip/hip_runtime.h>
#include <hip/hip_bf16.h>

// Self-attention with softmax over the QUERY axis (dim=1):
//   Q=XWq^T K=XWk^T V=XWv^T ; s = QK^T/16 ; attn[:,q,k] = exp(s)/sum_q exp(s)
//   out = attn @ V
// B=4, S=4096, D=Q_DIM=256.
//
// Path A: materialize P=exp(s/16) bf16 in ws; PV = LDS-staged GEMM using
//   global_load_lds (width 16), double-buffered, counted vmcnt(6), XOR-swizzled
//   LDS reads (pre-swizzled global source, linear LDS dest).
// Path B: flash-style fallback.

#define BATCH 4
#define SEQ 4096
#define DIM 256
#define ROWS (BATCH * SEQ)   // 16384

typedef __bf16 bf16x8 __attribute__((ext_vector_type(8)));
typedef float f32x4 __attribute__((ext_vector_type(4)));

__device__ __forceinline__ unsigned short f2b(float f) {
    union { float f; unsigned u; } v; v.f = f;
    unsigned u = v.u;
    u += 0x7FFFu + ((u >> 16) & 1u);   // RNE
    return (unsigned short)(u >> 16);
}

__device__ __forceinline__ float b2f(unsigned short h) {
    union { unsigned u; float f; } v; v.u = ((unsigned)h) << 16;
    return v.f;
}

// ---------------- vectorized cast f32 -> bf16 (n multiple of 8) ----------------
__global__ void cast_v8(const float* __restrict__ in,
                        unsigned short* __restrict__ out, int n8) {
    int i = blockIdx.x * blockDim.x + threadIdx.x;
    if (i >= n8) return;
    const float4 f0 = *(const float4*)(in + (size_t)i * 8);
    const float4 f1 = *(const float4*)(in + (size_t)i * 8 + 4);
    union { unsigned short u[8]; bf16x8 v; } o;
    o.u[0] = f2b(f0.x); o.u[1] = f2b(f0.y); o.u[2] = f2b(f0.z); o.u[3] = f2b(f0.w);
    o.u[4] = f2b(f1.x); o.u[5] = f2b(f1.y); o.u[6] = f2b(f1.z); o.u[7] = f2b(f1.w);
    *(bf16x8*)(out + (size_t)i * 8) = o.v;
}

// weights: 3 arrays of 65536 cast in one launch
__global__ void cast_w3(const float* __restrict__ w0, const float* __restrict__ w1,
                        const float* __restrict__ w2, unsigned short* __restrict__ o0,
                        unsigned short* __restrict__ o1, unsigned short* __restrict__ o2) {
    int t = blockIdx.x * blockDim.x + threadIdx.x;   // 3 * 8192
    int arr = t >> 13;
    int i = (t & 8191);
    const float* in = arr == 0 ? w0 : arr == 1 ? w1 : w2;
    unsigned short* out = arr == 0 ? o0 : arr == 1 ? o1 : o2;
    const float4 f0 = *(const float4*)(in + (size_t)i * 8);
    const float4 f1 = *(const float4*)(in + (size_t)i * 8 + 4);
    union { unsigned short u[8]; bf16x8 v; } o;
    o.u[0] = f2b(f0.x); o.u[1] = f2b(f0.y); o.u[2] = f2b(f0.z); o.u[3] = f2b(f0.w);
    o.u[4] = f2b(f1.x); o.u[5] = f2b(f1.y); o.u[6] = f2b(f1.z); o.u[7] = f2b(f1.w);
    *(bf16x8*)(out + (size_t)i * 8) = o.v;
}

// ------- QKV GEMM: z=0 Q, z=1 K, z=2 V(transposed store). out = X(Mx256)*W^T -------
__global__ __launch_bounds__(256) void gemm_qkv(const unsigned short* __restrict__ X,
                                                const unsigned short* __restrict__ Wq,
                                                const unsigned short* __restrict__ Wk,
                                                const unsigned short* __restrict__ Wv,
                                                unsigned short* __restrict__ Qo,
                                                unsigned short* __restrict__ Ko,
                                                unsigned short* __restrict__ Vo) {
    const int z = blockIdx.z;
    const unsigned short* Bw = z == 0 ? Wq : z == 1 ? Wk : Wv;
    unsigned short* out = z == 0 ? Qo : z == 1 ? Ko : Vo;
    const int trans = (z == 2);

    const int l = threadIdx.x & 63;
    const int w = threadIdx.x >> 6;
    const int wr = w >> 1, wc = w & 1;
    const int lr = l & 15, lk = l >> 4;
    const int rbase = blockIdx.x * 128 + wr * 64;
    const int cbase = blockIdx.y * 128 + wc * 64;

    f32x4 acc[4][4] = {};
#pragma unroll
    for (int d0 = 0; d0 < 256; d0 += 32) {
        bf16x8 a[4], b[4];
#pragma unroll
        for (int i = 0; i < 4; ++i)
            a[i] = *(const bf16x8*)(X + (size_t)(rbase + i * 16 + lr) * 256 + d0 + lk * 8);
#pragma unroll
        for (int j = 0; j < 4; ++j)
            b[j] = *(const bf16x8*)(Bw + (size_t)(cbase + j * 16 + lr) * 256 + d0 + lk * 8);
#pragma unroll
        for (int i = 0; i < 4; ++i)
#pragma unroll
            for (int j = 0; j < 4; ++j)
                acc[i][j] = __builtin_amdgcn_mfma_f32_16x16x32_bf16(a[i], b[j], acc[i][j], 0, 0, 0);
    }
#pragma unroll
    for (int i = 0; i < 4; ++i)
#pragma unroll
        for (int j = 0; j < 4; ++j)
#pragma unroll
            for (int r = 0; r < 4; ++r) {
                int row = rbase + i * 16 + lk * 4 + r;
                int col = cbase + j * 16 + lr;
                unsigned short v = f2b(acc[i][j][r]);
                if (!trans) out[(size_t)row * DIM + col] = v;
                else        out[(size_t)col * ROWS + row] = v;
            }
}

// ================= PATH A =================
// s-tile 128q x 128k; P=exp(s/16) -> LDS -> coalesced bf16x8 store to ws;
// column partial sums -> atomicAdd lsum. grid (32 k, 32 q, 4 b), block 256.
__global__ __launch_bounds__(256) void sp_kernel(const unsigned short* __restrict__ Qb,
                                                 const unsigned short* __restrict__ Kb,
                                                 unsigned short* __restrict__ P,
                                                 float* __restrict__ lsum) {
    __shared__ unsigned short Pt[128][136];
    const int l = threadIdx.x & 63;
    const int w = threadIdx.x >> 6;
    const int wr = w >> 1, wc = w & 1;
    const int lr = l & 15, lk = l >> 4;
    const int b = blockIdx.z;
    const int kb0 = blockIdx.x * 128;
    const int qb0 = blockIdx.y * 128;
    const int kbase = kb0 + wc * 64;
    const int qbase = qb0 + wr * 64;
    const unsigned short* Q = Qb + (size_t)b * SEQ * 256;
    const unsigned short* K = Kb + (size_t)b * SEQ * 256;
    unsigned short* Pb = P + (size_t)b * SEQ * SEQ;

    f32x4 acc[4][4] = {};
#pragma unroll
    for (int d0 = 0; d0 < 256; d0 += 32) {
        bf16x8 a[4], bb[4];
#pragma unroll
        for (int i = 0; i < 4; ++i)
            a[i] = *(const bf16x8*)(Q + (size_t)(qbase + i * 16 + lr) * 256 + d0 + lk * 8);
#pragma unroll
        for (int j = 0; j < 4; ++j)
            bb[j] = *(const bf16x8*)(K + (size_t)(kbase + j * 16 + lr) * 256 + d0 + lk * 8);
#pragma unroll
        for (int i = 0; i < 4; ++i)
#pragma unroll
            for (int j = 0; j < 4; ++j)
                acc[i][j] = __builtin_amdgcn_mfma_f32_16x16x32_bf16(a[i], bb[j], acc[i][j], 0, 0, 0);
    }
#pragma unroll
    for (int j = 0; j < 4; ++j) {
        float cs = 0.f;
#pragma unroll
        for (int i = 0; i < 4; ++i)
#pragma unroll
            for (int r = 0; r < 4; ++r) {
                float v = __expf(acc[i][j][r] * 0.0625f);
                cs += v;
                Pt[wr * 64 + i * 16 + lk * 4 + r][wc * 64 + j * 16 + lr] = f2b(v);
            }
        cs += __shfl_xor(cs, 16, 64);
        cs += __shfl_xor(cs, 32, 64);
        if (lk == 0)
            atomicAdd(&lsum[(size_t)b * SEQ + kbase + j * 16 + lr], cs);
    }
    __syncthreads();
#pragma unroll
    for (int it = 0; it < 8; ++it) {
        int n = it * 256 + threadIdx.x;
        int row = n >> 4;
        int ch = n & 15;
        *(bf16x8*)(Pb + (size_t)(qb0 + row) * SEQ + kb0 + ch * 8) =
            *(const bf16x8*)(&Pt[row][ch * 8]);
    }
}

// scale Vt rows by 1/l (vectorized x8): Vt[v][b*S+k] *= 1/l[b*S+k]
__global__ void scale_vt(unsigned short* __restrict__ Vt,
                         const float* __restrict__ lsum, int n8) {
    int i = blockIdx.x * blockDim.x + threadIdx.x;
    if (i >= n8) return;
    int col8 = (i & (ROWS / 8 - 1)) * 8;
    union { unsigned short u[8]; bf16x8 v; } d;
    d.v = *(const bf16x8*)(Vt + (size_t)i * 8);
#pragma unroll
    for (int j = 0; j < 8; ++j)
        d.u[j] = f2b(b2f(d.u[j]) / lsum[col8 + j]);
    *(bf16x8*)(Vt + (size_t)i * 8) = d.v;
}

// PV GEMM: out[q,v] = sum_k P[q,k] * Vt[v][b*S+k].  (P flat: [qglob][SEQ])
// Tile 64q x 128v, 256 thr (2x2 waves, wave 32q x 64v). BK=64.
// global_load_lds staging, double-buffered LDS (2 x 24KB), counted vmcnt(6).
// LDS rows are 128B: XOR swizzle slot^=(row&7) via pre-swizzled global source.
__global__ __launch_bounds__(256) void pv_gemm(const unsigned short* __restrict__ P,
                                               const unsigned short* __restrict__ Vt,
                                               float* __restrict__ out) {
    __shared__ unsigned short lds[2][12288];   // per buf: A 64x64 (8KB) | B 128x64 (16KB)
    const int t = threadIdx.x;
    const int w = t >> 6, l = t & 63;
    const int wq = w >> 1, wv = w & 1;
    const int lr = l & 15, lk = l >> 4;
    const int row_blk = blockIdx.x * 64;            // global q row base
    const int b = row_blk >> 12;
    const int vbase = blockIdx.y * 128;
    const size_t bS = (size_t)b * SEQ;

    // stage source pointers: 6 chunks of 1KB per thread-iteration (4 waves x 6 = 24KB)
    const int lrow = l >> 3;       // row within 8-row chunk
    const int lslot = l & 7;       // 16B slot within 128B row
    const unsigned short* src[6];
#pragma unroll
    for (int i = 0; i < 6; ++i) {
        const int chunk = i * 4 + w;
        if (chunk < 8) {           // A: P panel rows 0..63
            const int arow = chunk * 8 + lrow;
            src[i] = P + (size_t)(row_blk + arow) * SEQ + ((lslot ^ (arow & 7)) * 8);
        } else {                   // B: Vt panel rows 0..127
            const int vrow = (chunk - 8) * 8 + lrow;
            src[i] = Vt + (size_t)(vbase + vrow) * ROWS + bS + ((lslot ^ (vrow & 7)) * 8);
        }
    }

#define STAGE(bi) do {                                                        \
        _Pragma("unroll")                                                     \
        for (int i_ = 0; i_ < 6; ++i_) {                                      \
            const int chunk_ = i_ * 4 + w;                                    \
            __builtin_amdgcn_global_load_lds(                                 \
                (const unsigned int*)src[i_],                                 \
                (unsigned int*)&lds[bi][chunk_ * 512], 16, 0, 0);             \
        }                                                                     \
    } while (0)

#define ADV() do { _Pragma("unroll") for (int i_ = 0; i_ < 6; ++i_) src[i_] += 64; } while (0)

#define COMPUTE(bi) do {                                                      \
        const char* A_ = (const char*)&lds[bi][0];                            \
        const char* B_ = (const char*)&lds[bi][4096];                         \
        _Pragma("unroll")                                                     \
        for (int ks_ = 0; ks_ < 2; ++ks_) {                                   \
            bf16x8 af_[2], bf_[4];                                            \
            const int cb_ = ks_ * 64 + lk * 16;                               \
            _Pragma("unroll")                                                 \
            for (int i_ = 0; i_ < 2; ++i_) {                                  \
                const int row_ = wq * 32 + i_ * 16 + lr;                      \
                af_[i_] = *(const bf16x8*)(A_ + row_ * 128 +                  \
                                           (cb_ ^ ((row_ & 7) << 4)));        \
            }                                                                 \
            _Pragma("unroll")                                                 \
            for (int j_ = 0; j_ < 4; ++j_) {                                  \
                const int row_ = wv * 64 + j_ * 16 + lr;                      \
                bf_[j_] = *(const bf16x8*)(B_ + row_ * 128 +                  \
                                           (cb_ ^ ((row_ & 7) << 4)));        \
            }                                                                 \
            _Pragma("unroll")                                                 \
            for (int i_ = 0; i_ < 2; ++i_)                                    \
                _Pragma("unroll")                                             \
                for (int j_ = 0; j_ < 4; ++j_)                                \
                    acc[i_][j_] = __builtin_amdgcn_mfma_f32_16x16x32_bf16(    \
                        af_[i_], bf_[j_], acc[i_][j_], 0, 0, 0);              \
        }                                                                     \
    } while (0)

    f32x4 acc[2][4] = {};
    STAGE(0);                                   // k-chunk 0 -> buf0
#pragma unroll 1
    for (int tt = 0; tt < 64; tt += 2) {
        if (tt < 63) ADV();
        STAGE(1);                               // k-chunk tt+1 -> buf1
        asm volatile("s_waitcnt vmcnt(6)" ::: "memory");
        __builtin_amdgcn_s_barrier();
        COMPUTE(0);                             // k-chunk tt
        __builtin_amdgcn_s_barrier();

        if (tt + 1 < 63) ADV();
        STAGE(0);                               // k-chunk tt+2 -> buf0
        asm volatile("s_waitcnt vmcnt(6)" ::: "memory");
        __builtin_amdgcn_s_barrier();
        COMPUTE(1);                             // k-chunk tt+1
        __builtin_amdgcn_s_barrier();
    }
#undef STAGE
#undef ADV
#undef COMPUTE

#pragma unroll
    for (int i = 0; i < 2; ++i)
#pragma unroll
        for (int j = 0; j < 4; ++j)
#pragma unroll
            for (int r = 0; r < 4; ++r) {
                const int row = row_blk + wq * 32 + i * 16 + lk * 4 + r;
                const int col = vbase + wv * 64 + j * 16 + lr;
                out[(size_t)row * 256 + col] = acc[i][j][r];
            }
}

// ================= PATH B (fallback) =================
__global__ __launch_bounds__(256) void colsumexp(const unsigned short* __restrict__ Qb,
                                                 const unsigned short* __restrict__ Kb,
                                                 float* __restrict__ lsum) {
    const int l = threadIdx.x & 63;
    const int w = threadIdx.x >> 6;
    const int wr = w >> 1, wc = w & 1;
    const int lr = l & 15, lk = l >> 4;
    const int b = blockIdx.z;
    const int cbase = blockIdx.x * 128 + wc * 64;
    const unsigned short* Q = Qb + (size_t)b * SEQ * 256;
    const unsigned short* K = Kb + (size_t)b * SEQ * 256;

    float csum[4] = {0.f, 0.f, 0.f, 0.f};
    for (int qi = 0; qi < 16; ++qi) {
        const int rbase = blockIdx.y * 2048 + qi * 128 + wr * 64;
        f32x4 acc[4][4] = {};
#pragma unroll
        for (int d0 = 0; d0 < 256; d0 += 32) {
            bf16x8 a[4], bb[4];
#pragma unroll
            for (int i = 0; i < 4; ++i)
                a[i] = *(const bf16x8*)(Q + (size_t)(rbase + i * 16 + lr) * 256 + d0 + lk * 8);
#pragma unroll
            for (int j = 0; j < 4; ++j)
                bb[j] = *(const bf16x8*)(K + (size_t)(cbase + j * 16 + lr) * 256 + d0 + lk * 8);
#pragma unroll
            for (int i = 0; i < 4; ++i)
#pragma unroll
                for (int j = 0; j < 4; ++j)
                    acc[i][j] = __builtin_amdgcn_mfma_f32_16x16x32_bf16(a[i], bb[j], acc[i][j], 0, 0, 0);
        }
#pragma unroll
        for (int j = 0; j < 4; ++j) {
            float s = 0.f;
#pragma unroll
            for (int i = 0; i < 4; ++i)
#pragma unroll
                for (int r = 0; r < 4; ++r)
                    s += __expf(acc[i][j][r] * 0.0625f);
            csum[j] += s;
        }
    }
#pragma unroll
    for (int j = 0; j < 4; ++j) {
        float s = csum[j];
        s += __shfl_xor(s, 16, 64);
        s += __shfl_xor(s, 32, 64);
        if (lk == 0)
            atomicAdd(&lsum[(size_t)b * SEQ + cbase + j * 16 + lr], s);
    }
}

__global__ __launch_bounds__(256) void pv_kernel(const unsigned short* __restrict__ Qb,
                                                 const unsigned short* __restrict__ Kb,
                                                 const unsigned short* __restrict__ Vt,
                                                 float* __restrict__ out) {
    __shared__ unsigned short Pl[128][72];
    const int l = threadIdx.x & 63;
    const int w = threadIdx.x >> 6;
    const int wr = w >> 1, wc = w & 1;
    const int lr = l & 15, lk = l >> 4;
    const int b = blockIdx.z;
    const int qbase = blockIdx.x * 128;
    const int vbase = blockIdx.y * 128;
    const unsigned short* Q = Qb + (size_t)b * SEQ * 256;
    const unsigned short* K = Kb + (size_t)b * SEQ * 256;
    const unsigned short* V = Vt + (size_t)b * SEQ;

    f32x4 oacc[4][4] = {};
    for (int k0 = 0; k0 < SEQ; k0 += 64) {
        f32x4 sacc[4][2] = {};
#pragma unroll
        for (int d0 = 0; d0 < 256; d0 += 32) {
            bf16x8 a[4], bb[2];
#pragma unroll
            for (int i = 0; i < 4; ++i)
                a[i] = *(const bf16x8*)(Q + (size_t)(qbase + wr * 64 + i * 16 + lr) * 256 + d0 + lk * 8);
#pragma unroll
            for (int j = 0; j < 2; ++j)
                bb[j] = *(const bf16x8*)(K + (size_t)(k0 + wc * 32 + j * 16 + lr) * 256 + d0 + lk * 8);
#pragma unroll
            for (int i = 0; i < 4; ++i)
#pragma unroll
                for (int j = 0; j < 2; ++j)
                    sacc[i][j] = __builtin_amdgcn_mfma_f32_16x16x32_bf16(a[i], bb[j], sacc[i][j], 0, 0, 0);
        }
#pragma unroll
        for (int i = 0; i < 4; ++i)
#pragma unroll
            for (int j = 0; j < 2; ++j)
#pragma unroll
                for (int r = 0; r < 4; ++r)
                    Pl[wr * 64 + i * 16 + lk * 4 + r][wc * 32 + j * 16 + lr] =
                        f2b(__expf(sacc[i][j][r] * 0.0625f));
        __syncthreads();
#pragma unroll
        for (int ks = 0; ks < 2; ++ks) {
            bf16x8 a[4], bb[4];
#pragma unroll
            for (int i = 0; i < 4; ++i)
                a[i] = *(const bf16x8*)(&Pl[wr * 64 + i * 16 + lr][ks * 32 + lk * 8]);
#pragma unroll
            for (int j = 0; j < 4; ++j)
                bb[j] = *(const bf16x8*)(V + (size_t)(vbase + wc * 64 + j * 16 + lr) * ROWS + k0 + ks * 32 + lk * 8);
#pragma unroll
            for (int i = 0; i < 4; ++i)
#pragma unroll
                for (int j = 0; j < 4; ++j)
                    oacc[i][j] = __builtin_amdgcn_mfma_f32_16x16x32_bf16(a[i], bb[j], oacc[i][j], 0, 0, 0);
        }
        __syncthreads();
    }
    float* O = out + (size_t)b * SEQ * 256;
#pragma unroll
    for (int i = 0; i < 4; ++i)
#pragma unroll
        for (int j = 0; j < 4; ++j)
#pragma unroll
            for (int r = 0; r < 4; ++r) {
                int row = qbase + wr * 64 + i * 16 + lk * 4 + r;
                int col = vbase + wc * 64 + j * 16 + lr;
                O[(size_t)row * 256 + col] = oacc[i][j][r];
            }
}

extern "C" void kernel_launch(void* const* d_in, const int* in_sizes, int n_in,
                              void* d_out, int out_size, void* d_ws, size_t ws_size,
                              hipStream_t stream) {
    const float* x  = (const float*)d_in[0];
    const float* wq = (const float*)d_in[1];
    const float* wk = (const float*)d_in[2];
    const float* wv = (const float*)d_in[3];
    float* out = (float*)d_out;

    char* ws = (char*)d_ws;
    unsigned short* Xb  = (unsigned short*)(ws + 0);
    unsigned short* Qb  = (unsigned short*)(ws + 8388608);
    unsigned short* Kb  = (unsigned short*)(ws + 16777216);
    unsigned short* Vt  = (unsigned short*)(ws + 25165824);
    unsigned short* Wqb = (unsigned short*)(ws + 33554432);
    unsigned short* Wkb = (unsigned short*)(ws + 33685504);
    unsigned short* Wvb = (unsigned short*)(ws + 33816576);
    float*          lsum = (float*)(ws + 33947648);
    unsigned short* Pbuf = (unsigned short*)(ws + 34013184);
    const size_t need_A = 34013184 + (size_t)BATCH * SEQ * SEQ * 2;   // ~168 MB

    const int n_x = ROWS * DIM;      // 4194304

    cast_v8<<<(n_x / 8 + 255) / 256, 256, 0, stream>>>(x, Xb, n_x / 8);
    cast_w3<<<(3 * 8192 + 255) / 256, 256, 0, stream>>>(wq, wk, wv, Wqb, Wkb, Wvb);

    dim3 gg(ROWS / 128, DIM / 128, 3);   // (128, 2, 3)
    gemm_qkv<<<gg, 256, 0, stream>>>(Xb, Wqb, Wkb, Wvb, Qb, Kb, Vt);

    hipMemsetAsync(lsum, 0, (size_t)BATCH * SEQ * sizeof(float), stream);

    if (ws_size >= need_A) {
        dim3 gs(SEQ / 128, SEQ / 128, BATCH);   // (32, 32, 4)
        sp_kernel<<<gs, 256, 0, stream>>>(Qb, Kb, Pbuf, lsum);
        scale_vt<<<(n_x / 8 + 255) / 256, 256, 0, stream>>>(Vt, lsum, n_x / 8);
        dim3 gp(ROWS / 64, DIM / 128);          // (256, 2) = 512 blocks
        pv_gemm<<<gp, 256, 0, stream>>>(Pbuf, Vt, out);
    } else {
        dim3 gs(SEQ / 128, 2, BATCH);
        colsumexp<<<gs, 256, 0, stream>>>(Qb, Kb, lsum);
        scale_vt<<<(n_x / 8 + 255) / 256, 256, 0, stream>>>(Vt, lsum, n_x / 8);
        dim3 gp(SEQ / 128, DIM / 128, BATCH);
        pv_kernel<<<gp, 256, 0, stream>>>(Qb, Kb, Vt, out);
    }
}

// Round 7
// 163.246 us; speedup vs baseline: 2.1878x; 1.3476x over previous
//
#include <hip/hip_runtime.h>
#include <hip/hip_bf16.h>

// Self-attention with softmax over the QUERY axis (dim=1):
//   Q=XWq^T K=XWk^T V=XWv^T ; s = QK^T/16 ; attn[:,q,k] = exp(s)/sum_q exp(s)
//   out = attn @ V
// B=4, S=4096, D=Q_DIM=256.
//
// Path A: materialize P=exp(s/16) bf16 in ws.
//   sp_kernel: QK^T via global_load_lds staging (BK=64, counted vmcnt(8),
//     (row&7) XOR swizzle, sched_barrier(0) fences), fused exp + col-sum,
//     Pt output tile aliased over the staging LDS.
//   pv_gemm: same proven staging pattern (vmcnt(6)), now also fenced.
// Path B: flash-style fallback.

#define BATCH 4
#define SEQ 4096
#define DIM 256
#define ROWS (BATCH * SEQ)   // 16384

typedef __bf16 bf16x8 __attribute__((ext_vector_type(8)));
typedef float f32x4 __attribute__((ext_vector_type(4)));

#define SB() __builtin_amdgcn_sched_barrier(0)

__device__ __forceinline__ unsigned short f2b(float f) {
    union { float f; unsigned u; } v; v.f = f;
    unsigned u = v.u;
    u += 0x7FFFu + ((u >> 16) & 1u);   // RNE
    return (unsigned short)(u >> 16);
}

__device__ __forceinline__ float b2f(unsigned short h) {
    union { unsigned u; float f; } v; v.u = ((unsigned)h) << 16;
    return v.f;
}

// ---------------- vectorized cast f32 -> bf16 (n multiple of 8) ----------------
__global__ void cast_v8(const float* __restrict__ in,
                        unsigned short* __restrict__ out, int n8) {
    int i = blockIdx.x * blockDim.x + threadIdx.x;
    if (i >= n8) return;
    const float4 f0 = *(const float4*)(in + (size_t)i * 8);
    const float4 f1 = *(const float4*)(in + (size_t)i * 8 + 4);
    union { unsigned short u[8]; bf16x8 v; } o;
    o.u[0] = f2b(f0.x); o.u[1] = f2b(f0.y); o.u[2] = f2b(f0.z); o.u[3] = f2b(f0.w);
    o.u[4] = f2b(f1.x); o.u[5] = f2b(f1.y); o.u[6] = f2b(f1.z); o.u[7] = f2b(f1.w);
    *(bf16x8*)(out + (size_t)i * 8) = o.v;
}

// weights: 3 arrays of 65536 cast in one launch
__global__ void cast_w3(const float* __restrict__ w0, const float* __restrict__ w1,
                        const float* __restrict__ w2, unsigned short* __restrict__ o0,
                        unsigned short* __restrict__ o1, unsigned short* __restrict__ o2) {
    int t = blockIdx.x * blockDim.x + threadIdx.x;   // 3 * 8192
    int arr = t >> 13;
    int i = (t & 8191);
    const float* in = arr == 0 ? w0 : arr == 1 ? w1 : w2;
    unsigned short* out = arr == 0 ? o0 : arr == 1 ? o1 : o2;
    const float4 f0 = *(const float4*)(in + (size_t)i * 8);
    const float4 f1 = *(const float4*)(in + (size_t)i * 8 + 4);
    union { unsigned short u[8]; bf16x8 v; } o;
    o.u[0] = f2b(f0.x); o.u[1] = f2b(f0.y); o.u[2] = f2b(f0.z); o.u[3] = f2b(f0.w);
    o.u[4] = f2b(f1.x); o.u[5] = f2b(f1.y); o.u[6] = f2b(f1.z); o.u[7] = f2b(f1.w);
    *(bf16x8*)(out + (size_t)i * 8) = o.v;
}

// ------- QKV GEMM: z=0 Q, z=1 K, z=2 V(transposed store). out = X(Mx256)*W^T -------
__global__ __launch_bounds__(256) void gemm_qkv(const unsigned short* __restrict__ X,
                                                const unsigned short* __restrict__ Wq,
                                                const unsigned short* __restrict__ Wk,
                                                const unsigned short* __restrict__ Wv,
                                                unsigned short* __restrict__ Qo,
                                                unsigned short* __restrict__ Ko,
                                                unsigned short* __restrict__ Vo) {
    const int z = blockIdx.z;
    const unsigned short* Bw = z == 0 ? Wq : z == 1 ? Wk : Wv;
    unsigned short* out = z == 0 ? Qo : z == 1 ? Ko : Vo;
    const int trans = (z == 2);

    const int l = threadIdx.x & 63;
    const int w = threadIdx.x >> 6;
    const int wr = w >> 1, wc = w & 1;
    const int lr = l & 15, lk = l >> 4;
    const int rbase = blockIdx.x * 128 + wr * 64;
    const int cbase = blockIdx.y * 128 + wc * 64;

    f32x4 acc[4][4] = {};
#pragma unroll
    for (int d0 = 0; d0 < 256; d0 += 32) {
        bf16x8 a[4], b[4];
#pragma unroll
        for (int i = 0; i < 4; ++i)
            a[i] = *(const bf16x8*)(X + (size_t)(rbase + i * 16 + lr) * 256 + d0 + lk * 8);
#pragma unroll
        for (int j = 0; j < 4; ++j)
            b[j] = *(const bf16x8*)(Bw + (size_t)(cbase + j * 16 + lr) * 256 + d0 + lk * 8);
#pragma unroll
        for (int i = 0; i < 4; ++i)
#pragma unroll
            for (int j = 0; j < 4; ++j)
                acc[i][j] = __builtin_amdgcn_mfma_f32_16x16x32_bf16(a[i], b[j], acc[i][j], 0, 0, 0);
    }
#pragma unroll
    for (int i = 0; i < 4; ++i)
#pragma unroll
        for (int j = 0; j < 4; ++j)
#pragma unroll
            for (int r = 0; r < 4; ++r) {
                int row = rbase + i * 16 + lk * 4 + r;
                int col = cbase + j * 16 + lr;
                unsigned short v = f2b(acc[i][j][r]);
                if (!trans) out[(size_t)row * DIM + col] = v;
                else        out[(size_t)col * ROWS + row] = v;
            }
}

// ================= PATH A =================
// sp_kernel: s-tile 128q x 128k via staged GEMM (pv_gemm's exact pattern,
// BK=64, 8-slot swizzle, unroll-1 two-phase loop, vmcnt(8), fenced);
// P=exp(s/16) -> Pt (aliases staging) -> coalesced store; col sums -> atomic.
// grid (32 k, 32 q, 4 b), 256 thr. LDS = 2 x 32KB staging, Pt aliased.
__global__ __launch_bounds__(256) void sp_kernel(const unsigned short* __restrict__ Qb,
                                                 const unsigned short* __restrict__ Kb,
                                                 unsigned short* __restrict__ P,
                                                 float* __restrict__ lsum) {
    __shared__ unsigned short smem[32768];   // 64KB: [2][16384]; Pt[128][136] aliased
    const int t = threadIdx.x;
    const int w = t >> 6, l = t & 63;
    const int wq = w >> 1, wk = w & 1;
    const int lr = l & 15, lk = l >> 4;
    const int b = blockIdx.z;
    const int kb0 = blockIdx.x * 128;
    const int qb0 = blockIdx.y * 128;
    const unsigned short* Q = Qb + (size_t)b * SEQ * 256;
    const unsigned short* K = Kb + (size_t)b * SEQ * 256;
    unsigned short* Pb = P + (size_t)b * SEQ * SEQ;

    // staging: 32 chunks of 1KB (8 rows x 128B). chunks 0-15 = Q, 16-31 = K.
    // wave w loads chunks {i*4+w : i in [0,8)}. swizzle: slot s <- global s^(row&7)
    const int lrow = l >> 3;       // row within chunk
    const int lslot = l & 7;       // 16B slot within 128B row
    const unsigned short* src[8];
#pragma unroll
    for (int i = 0; i < 8; ++i) {
        const int chunk = i * 4 + w;
        if (chunk < 16) {
            const int arow = chunk * 8 + lrow;
            src[i] = Q + (size_t)(qb0 + arow) * 256 + ((lslot ^ (arow & 7)) * 8);
        } else {
            const int krow = (chunk - 16) * 8 + lrow;
            src[i] = K + (size_t)(kb0 + krow) * 256 + ((lslot ^ (krow & 7)) * 8);
        }
    }

#define SPSTAGE(bi) do {                                                      \
        _Pragma("unroll")                                                     \
        for (int i_ = 0; i_ < 8; ++i_) {                                      \
            const int chunk_ = i_ * 4 + w;                                    \
            __builtin_amdgcn_global_load_lds(                                 \
                (const unsigned int*)src[i_],                                 \
                (unsigned int*)&smem[(bi) * 16384 + chunk_ * 512], 16, 0, 0); \
        }                                                                     \
    } while (0)
#define SPADV() do { _Pragma("unroll") for (int x_ = 0; x_ < 8; ++x_) src[x_] += 64; } while (0)

#define SPCOMPUTE(bi) do {                                                    \
        const char* A_ = (const char*)smem + (bi) * 32768;                    \
        const char* B_ = A_ + 16384;                                          \
        _Pragma("unroll")                                                     \
        for (int ks_ = 0; ks_ < 2; ++ks_) {                                   \
            bf16x8 af_[4], bf_[4];                                            \
            const int cb_ = ks_ * 64 + lk * 16;                               \
            _Pragma("unroll")                                                 \
            for (int i_ = 0; i_ < 4; ++i_) {                                  \
                const int row_ = wq * 64 + i_ * 16 + lr;                      \
                af_[i_] = *(const bf16x8*)(A_ + row_ * 128 +                  \
                                           (cb_ ^ ((row_ & 7) << 4)));        \
            }                                                                 \
            _Pragma("unroll")                                                 \
            for (int j_ = 0; j_ < 4; ++j_) {                                  \
                const int row_ = wk * 64 + j_ * 16 + lr;                      \
                bf_[j_] = *(const bf16x8*)(B_ + row_ * 128 +                  \
                                           (cb_ ^ ((row_ & 7) << 4)));        \
            }                                                                 \
            _Pragma("unroll")                                                 \
            for (int i_ = 0; i_ < 4; ++i_)                                    \
                _Pragma("unroll")                                             \
                for (int j_ = 0; j_ < 4; ++j_)                                \
                    acc[i_][j_] = __builtin_amdgcn_mfma_f32_16x16x32_bf16(    \
                        af_[i_], bf_[j_], acc[i_][j_], 0, 0, 0);              \
        }                                                                     \
    } while (0)

    f32x4 acc[4][4] = {};
    SPSTAGE(0);                                  // d-chunk 0 -> buf0
#pragma unroll 1
    for (int tt = 0; tt < 4; tt += 2) {
        SPADV();
        SPSTAGE(1);                              // d-chunk tt+1 -> buf1
        SB(); asm volatile("s_waitcnt vmcnt(8)" ::: "memory"); SB();
        __builtin_amdgcn_s_barrier(); SB();
        SPCOMPUTE(0);                            // d-chunk tt
        SB(); __builtin_amdgcn_s_barrier(); SB();

        if (tt == 0) {
            SPADV();
            SPSTAGE(0);                          // d-chunk 2 -> buf0
            SB(); asm volatile("s_waitcnt vmcnt(8)" ::: "memory"); SB();
        } else {
            SB(); asm volatile("s_waitcnt vmcnt(0)" ::: "memory"); SB();
        }
        __builtin_amdgcn_s_barrier(); SB();
        SPCOMPUTE(1);                            // d-chunk tt+1
        SB(); __builtin_amdgcn_s_barrier(); SB();
    }
#undef SPSTAGE
#undef SPADV
#undef SPCOMPUTE

    // exp epilogue into Pt (aliases smem; staging consumed, final barrier passed)
    unsigned short* Pt = smem;   // [128][136]
#pragma unroll
    for (int j = 0; j < 4; ++j) {
        float cs = 0.f;
#pragma unroll
        for (int i = 0; i < 4; ++i)
#pragma unroll
            for (int r = 0; r < 4; ++r) {
                float v = __expf(acc[i][j][r] * 0.0625f);
                cs += v;
                Pt[(wq * 64 + i * 16 + lk * 4 + r) * 136 + wk * 64 + j * 16 + lr] = f2b(v);
            }
        cs += __shfl_xor(cs, 16, 64);
        cs += __shfl_xor(cs, 32, 64);
        if (lk == 0)
            atomicAdd(&lsum[(size_t)b * SEQ + kb0 + wk * 64 + j * 16 + lr], cs);
    }
    __syncthreads();
    // coalesced store: 128 rows x 16 chunks(16B)
#pragma unroll
    for (int it = 0; it < 8; ++it) {
        int n = it * 256 + t;
        int row = n >> 4;
        int ch = n & 15;
        *(bf16x8*)(Pb + (size_t)(qb0 + row) * SEQ + kb0 + ch * 8) =
            *(const bf16x8*)(&Pt[row * 136 + ch * 8]);
    }
}

// scale Vt rows by 1/l (vectorized x8): Vt[v][b*S+k] *= 1/l[b*S+k]
__global__ void scale_vt(unsigned short* __restrict__ Vt,
                         const float* __restrict__ lsum, int n8) {
    int i = blockIdx.x * blockDim.x + threadIdx.x;
    if (i >= n8) return;
    int col8 = (i & (ROWS / 8 - 1)) * 8;
    union { unsigned short u[8]; bf16x8 v; } d;
    d.v = *(const bf16x8*)(Vt + (size_t)i * 8);
#pragma unroll
    for (int j = 0; j < 8; ++j)
        d.u[j] = f2b(b2f(d.u[j]) / lsum[col8 + j]);
    *(bf16x8*)(Vt + (size_t)i * 8) = d.v;
}

// PV GEMM: out[q,v] = sum_k P[q,k] * Vt[v][b*S+k].  (P flat: [qglob][SEQ])
// Tile 64q x 128v, 256 thr (2x2 waves). BK=64, double-buffered, vmcnt(6), fenced.
__global__ __launch_bounds__(256) void pv_gemm(const unsigned short* __restrict__ P,
                                               const unsigned short* __restrict__ Vt,
                                               float* __restrict__ out) {
    __shared__ unsigned short lds[2][12288];   // per buf: A 64x64 (8KB) | B 128x64 (16KB)
    const int t = threadIdx.x;
    const int w = t >> 6, l = t & 63;
    const int wq = w >> 1, wv = w & 1;
    const int lr = l & 15, lk = l >> 4;
    const int row_blk = blockIdx.x * 64;            // global q row base
    const int b = row_blk >> 12;
    const int vbase = blockIdx.y * 128;
    const size_t bS = (size_t)b * SEQ;

    const int lrow = l >> 3;
    const int lslot = l & 7;
    const unsigned short* src[6];
#pragma unroll
    for (int i = 0; i < 6; ++i) {
        const int chunk = i * 4 + w;
        if (chunk < 8) {           // A: P panel rows 0..63
            const int arow = chunk * 8 + lrow;
            src[i] = P + (size_t)(row_blk + arow) * SEQ + ((lslot ^ (arow & 7)) * 8);
        } else {                   // B: Vt panel rows 0..127
            const int vrow = (chunk - 8) * 8 + lrow;
            src[i] = Vt + (size_t)(vbase + vrow) * ROWS + bS + ((lslot ^ (vrow & 7)) * 8);
        }
    }

#define STAGE(bi) do {                                                        \
        _Pragma("unroll")                                                     \
        for (int i_ = 0; i_ < 6; ++i_) {                                      \
            const int chunk_ = i_ * 4 + w;                                    \
            __builtin_amdgcn_global_load_lds(                                 \
                (const unsigned int*)src[i_],                                 \
                (unsigned int*)&lds[bi][chunk_ * 512], 16, 0, 0);             \
        }                                                                     \
    } while (0)

#define ADV() do { _Pragma("unroll") for (int i_ = 0; i_ < 6; ++i_) src[i_] += 64; } while (0)

#define COMPUTE(bi) do {                                                      \
        const char* A_ = (const char*)&lds[bi][0];                            \
        const char* B_ = (const char*)&lds[bi][4096];                         \
        _Pragma("unroll")                                                     \
        for (int ks_ = 0; ks_ < 2; ++ks_) {                                   \
            bf16x8 af_[2], bf_[4];                                            \
            const int cb_ = ks_ * 64 + lk * 16;                               \
            _Pragma("unroll")                                                 \
            for (int i_ = 0; i_ < 2; ++i_) {                                  \
                const int row_ = wq * 32 + i_ * 16 + lr;                      \
                af_[i_] = *(const bf16x8*)(A_ + row_ * 128 +                  \
                                           (cb_ ^ ((row_ & 7) << 4)));        \
            }                                                                 \
            _Pragma("unroll")                                                 \
            for (int j_ = 0; j_ < 4; ++j_) {                                  \
                const int row_ = wv * 64 + j_ * 16 + lr;                      \
                bf_[j_] = *(const bf16x8*)(B_ + row_ * 128 +                  \
                                           (cb_ ^ ((row_ & 7) << 4)));        \
            }                                                                 \
            _Pragma("unroll")                                                 \
            for (int i_ = 0; i_ < 2; ++i_)                                    \
                _Pragma("unroll")                                             \
                for (int j_ = 0; j_ < 4; ++j_)                                \
                    acc[i_][j_] = __builtin_amdgcn_mfma_f32_16x16x32_bf16(    \
                        af_[i_], bf_[j_], acc[i_][j_], 0, 0, 0);              \
        }                                                                     \
    } while (0)

    f32x4 acc[2][4] = {};
    STAGE(0);                                   // k-chunk 0 -> buf0
#pragma unroll 1
    for (int tt = 0; tt < 64; tt += 2) {
        if (tt < 63) ADV();
        STAGE(1);                               // k-chunk tt+1 -> buf1
        SB(); asm volatile("s_waitcnt vmcnt(6)" ::: "memory"); SB();
        __builtin_amdgcn_s_barrier(); SB();
        COMPUTE(0);                             // k-chunk tt
        SB(); __builtin_amdgcn_s_barrier(); SB();

        if (tt + 1 < 63) ADV();
        STAGE(0);                               // k-chunk tt+2 -> buf0
        SB(); asm volatile("s_waitcnt vmcnt(6)" ::: "memory"); SB();
        __builtin_amdgcn_s_barrier(); SB();
        COMPUTE(1);                             // k-chunk tt+1
        SB(); __builtin_amdgcn_s_barrier(); SB();
    }
#undef STAGE
#undef ADV
#undef COMPUTE

#pragma unroll
    for (int i = 0; i < 2; ++i)
#pragma unroll
        for (int j = 0; j < 4; ++j)
#pragma unroll
            for (int r = 0; r < 4; ++r) {
                const int row = row_blk + wq * 32 + i * 16 + lk * 4 + r;
                const int col = vbase + wv * 64 + j * 16 + lr;
                out[(size_t)row * 256 + col] = acc[i][j][r];
            }
}

// ================= PATH B (fallback) =================
__global__ __launch_bounds__(256) void colsumexp(const unsigned short* __restrict__ Qb,
                                                 const unsigned short* __restrict__ Kb,
                                                 float* __restrict__ lsum) {
    const int l = threadIdx.x & 63;
    const int w = threadIdx.x >> 6;
    const int wr = w >> 1, wc = w & 1;
    const int lr = l & 15, lk = l >> 4;
    const int b = blockIdx.z;
    const int cbase = blockIdx.x * 128 + wc * 64;
    const unsigned short* Q = Qb + (size_t)b * SEQ * 256;
    const unsigned short* K = Kb + (size_t)b * SEQ * 256;

    float csum[4] = {0.f, 0.f, 0.f, 0.f};
    for (int qi = 0; qi < 16; ++qi) {
        const int rbase = blockIdx.y * 2048 + qi * 128 + wr * 64;
        f32x4 acc[4][4] = {};
#pragma unroll
        for (int d0 = 0; d0 < 256; d0 += 32) {
            bf16x8 a[4], bb[4];
#pragma unroll
            for (int i = 0; i < 4; ++i)
                a[i] = *(const bf16x8*)(Q + (size_t)(rbase + i * 16 + lr) * 256 + d0 + lk * 8);
#pragma unroll
            for (int j = 0; j < 4; ++j)
                bb[j] = *(const bf16x8*)(K + (size_t)(cbase + j * 16 + lr) * 256 + d0 + lk * 8);
#pragma unroll
            for (int i = 0; i < 4; ++i)
#pragma unroll
                for (int j = 0; j < 4; ++j)
                    acc[i][j] = __builtin_amdgcn_mfma_f32_16x16x32_bf16(a[i], bb[j], acc[i][j], 0, 0, 0);
        }
#pragma unroll
        for (int j = 0; j < 4; ++j) {
            float s = 0.f;
#pragma unroll
            for (int i = 0; i < 4; ++i)
#pragma unroll
                for (int r = 0; r < 4; ++r)
                    s += __expf(acc[i][j][r] * 0.0625f);
            csum[j] += s;
        }
    }
#pragma unroll
    for (int j = 0; j < 4; ++j) {
        float s = csum[j];
        s += __shfl_xor(s, 16, 64);
        s += __shfl_xor(s, 32, 64);
        if (lk == 0)
            atomicAdd(&lsum[(size_t)b * SEQ + cbase + j * 16 + lr], s);
    }
}

__global__ __launch_bounds__(256) void pv_kernel(const unsigned short* __restrict__ Qb,
                                                 const unsigned short* __restrict__ Kb,
                                                 const unsigned short* __restrict__ Vt,
                                                 float* __restrict__ out) {
    __shared__ unsigned short Pl[128][72];
    const int l = threadIdx.x & 63;
    const int w = threadIdx.x >> 6;
    const int wr = w >> 1, wc = w & 1;
    const int lr = l & 15, lk = l >> 4;
    const int b = blockIdx.z;
    const int qbase = blockIdx.x * 128;
    const int vbase = blockIdx.y * 128;
    const unsigned short* Q = Qb + (size_t)b * SEQ * 256;
    const unsigned short* K = Kb + (size_t)b * SEQ * 256;
    const unsigned short* V = Vt + (size_t)b * SEQ;

    f32x4 oacc[4][4] = {};
    for (int k0 = 0; k0 < SEQ; k0 += 64) {
        f32x4 sacc[4][2] = {};
#pragma unroll
        for (int d0 = 0; d0 < 256; d0 += 32) {
            bf16x8 a[4], bb[2];
#pragma unroll
            for (int i = 0; i < 4; ++i)
                a[i] = *(const bf16x8*)(Q + (size_t)(qbase + wr * 64 + i * 16 + lr) * 256 + d0 + lk * 8);
#pragma unroll
            for (int j = 0; j < 2; ++j)
                bb[j] = *(const bf16x8*)(K + (size_t)(k0 + wc * 32 + j * 16 + lr) * 256 + d0 + lk * 8);
#pragma unroll
            for (int i = 0; i < 4; ++i)
#pragma unroll
                for (int j = 0; j < 2; ++j)
                    sacc[i][j] = __builtin_amdgcn_mfma_f32_16x16x32_bf16(a[i], bb[j], sacc[i][j], 0, 0, 0);
        }
#pragma unroll
        for (int i = 0; i < 4; ++i)
#pragma unroll
            for (int j = 0; j < 2; ++j)
#pragma unroll
                for (int r = 0; r < 4; ++r)
                    Pl[wr * 64 + i * 16 + lk * 4 + r][wc * 32 + j * 16 + lr] =
                        f2b(__expf(sacc[i][j][r] * 0.0625f));
        __syncthreads();
#pragma unroll
        for (int ks = 0; ks < 2; ++ks) {
            bf16x8 a[4], bb[4];
#pragma unroll
            for (int i = 0; i < 4; ++i)
                a[i] = *(const bf16x8*)(&Pl[wr * 64 + i * 16 + lr][ks * 32 + lk * 8]);
#pragma unroll
            for (int j = 0; j < 4; ++j)
                bb[j] = *(const bf16x8*)(V + (size_t)(vbase + wc * 64 + j * 16 + lr) * ROWS + k0 + ks * 32 + lk * 8);
#pragma unroll
            for (int i = 0; i < 4; ++i)
#pragma unroll
                for (int j = 0; j < 4; ++j)
                    oacc[i][j] = __builtin_amdgcn_mfma_f32_16x16x32_bf16(a[i], bb[j], oacc[i][j], 0, 0, 0);
        }
        __syncthreads();
    }
    float* O = out + (size_t)b * SEQ * 256;
#pragma unroll
    for (int i = 0; i < 4; ++i)
#pragma unroll
        for (int j = 0; j < 4; ++j)
#pragma unroll
            for (int r = 0; r < 4; ++r) {
                int row = qbase + wr * 64 + i * 16 + lk * 4 + r;
                int col = vbase + wc * 64 + j * 16 + lr;
                O[(size_t)row * 256 + col] = oacc[i][j][r];
            }
}

extern "C" void kernel_launch(void* const* d_in, const int* in_sizes, int n_in,
                              void* d_out, int out_size, void* d_ws, size_t ws_size,
                              hipStream_t stream) {
    const float* x  = (const float*)d_in[0];
    const float* wq = (const float*)d_in[1];
    const float* wk = (const float*)d_in[2];
    const float* wv = (const float*)d_in[3];
    float* out = (float*)d_out;

    char* ws = (char*)d_ws;
    unsigned short* Xb  = (unsigned short*)(ws + 0);
    unsigned short* Qb  = (unsigned short*)(ws + 8388608);
    unsigned short* Kb  = (unsigned short*)(ws + 16777216);
    unsigned short* Vt  = (unsigned short*)(ws + 25165824);
    unsigned short* Wqb = (unsigned short*)(ws + 33554432);
    unsigned short* Wkb = (unsigned short*)(ws + 33685504);
    unsigned short* Wvb = (unsigned short*)(ws + 33816576);
    float*          lsum = (float*)(ws + 33947648);
    unsigned short* Pbuf = (unsigned short*)(ws + 34013184);
    const size_t need_A = 34013184 + (size_t)BATCH * SEQ * SEQ * 2;   // ~168 MB

    const int n_x = ROWS * DIM;      // 4194304

    cast_v8<<<(n_x / 8 + 255) / 256, 256, 0, stream>>>(x, Xb, n_x / 8);
    cast_w3<<<(3 * 8192 + 255) / 256, 256, 0, stream>>>(wq, wk, wv, Wqb, Wkb, Wvb);

    dim3 gg(ROWS / 128, DIM / 128, 3);   // (128, 2, 3)
    gemm_qkv<<<gg, 256, 0, stream>>>(Xb, Wqb, Wkb, Wvb, Qb, Kb, Vt);

    hipMemsetAsync(lsum, 0, (size_t)BATCH * SEQ * sizeof(float), stream);

    if (ws_size >= need_A) {
        dim3 gs(SEQ / 128, SEQ / 128, BATCH);   // (32, 32, 4)
        sp_kernel<<<gs, 256, 0, stream>>>(Qb, Kb, Pbuf, lsum);
        scale_vt<<<(n_x / 8 + 255) / 256, 256, 0, stream>>>(Vt, lsum, n_x / 8);
        dim3 gp(ROWS / 64, DIM / 128);          // (256, 2) = 512 blocks
        pv_gemm<<<gp, 256, 0, stream>>>(Pbuf, Vt, out);
    } else {
        dim3 gs(SEQ / 128, 2, BATCH);
        colsumexp<<<gs, 256, 0, stream>>>(Qb, Kb, lsum);
        scale_vt<<<(n_x / 8 + 255) / 256, 256, 0, stream>>>(Vt, lsum, n_x / 8);
        dim3 gp(SEQ / 128, DIM / 128, BATCH);
        pv_kernel<<<gp, 256, 0, stream>>>(Qb, Kb, Vt, out);
    }
}